// Round 1
// baseline (14801.494 us; speedup 1.0000x reference)
//
#include <hip/hip_runtime.h>

// ---------------------------------------------------------------------------
// VehicleTrajectoryDecoder: B=32, N=256, D=512, H=8 (dh=64), T=60, DFF=2048.
// Strategy: KV-cache the self-attention (reference is O(T^3), we do O(T^2)),
// precompute spatial/cross K,V from H_v_all once, then 5 small kernels per
// step (strictly sequential chain). All fp32 this round (accuracy anchor).
// ---------------------------------------------------------------------------

#define NB 32
#define NN 256
#define DD 512
#define NH 8
#define DH 64
#define TT 60
#define DF 2048

// ---- workspace layout (floats) --------------------------------------------
constexpr size_t SZ_KV  = (size_t)NB * NN * DD;        // 4194304
constexpr size_t SZ_SA  = (size_t)NB * TT * DD;        // 983040
constexpr size_t OFF_KS  = 0;
constexpr size_t OFF_VS  = OFF_KS  + SZ_KV;
constexpr size_t OFF_KC  = OFF_VS  + SZ_KV;
constexpr size_t OFF_VC  = OFF_KC  + SZ_KV;
constexpr size_t OFF_KST = OFF_VC  + SZ_KV;            // Ks transposed [b][d][n]
constexpr size_t OFF_KCT = OFF_KST + SZ_KV;            // Kc transposed [b][d][n]
constexpr size_t OFF_KSA = OFF_KCT + SZ_KV;            // self-attn K cache [b][t][d]
constexpr size_t OFF_VSA = OFF_KSA + SZ_SA;
constexpr size_t OFF_WT  = OFF_VSA + SZ_SA;            // 8 transposed 512x512 weights
constexpr size_t OFF_W1T = OFF_WT  + 8ull * DD * DD;   // [512][2048]
constexpr size_t OFF_W2T = OFF_W1T + (size_t)DD * DF;  // [2048][512]
constexpr size_t OFF_X   = OFF_W2T + (size_t)DF * DD;  // xcur [32][512]
constexpr size_t OFF_QSA = OFF_X   + (size_t)NB * DD;
constexpr size_t OFF_QS  = OFF_QSA + (size_t)NB * DD;
constexpr size_t OFF_Z   = OFF_QS  + (size_t)NB * DD;
constexpr size_t OFF_U3  = OFF_Z   + (size_t)NB * DD;
constexpr size_t OFF_H   = OFF_U3  + (size_t)NB * DD;  // hbuf [32][2048]
// end = OFF_H + 65536 = 31,473,664 floats = 125.9 MB  (requires ws >= 126MB)

// ---- helpers ----------------------------------------------------------------
__device__ __forceinline__ void ln_stats512(float v, float* red, int tid,
                                            float& mean, float& invstd) {
  float s = v, q = v * v;
  #pragma unroll
  for (int m = 32; m >= 1; m >>= 1) { s += __shfl_xor(s, m); q += __shfl_xor(q, m); }
  if ((tid & 63) == 0) { red[tid >> 6] = s; red[8 + (tid >> 6)] = q; }
  __syncthreads();
  if (tid == 0) {
    float ss = 0.f, qq = 0.f;
    #pragma unroll
    for (int i = 0; i < 8; i++) { ss += red[i]; qq += red[8 + i]; }
    float m_ = ss * (1.0f / 512.0f);
    float var = qq * (1.0f / 512.0f) - m_ * m_;
    red[16] = m_;
    red[17] = rsqrtf(var + 1e-5f);
  }
  __syncthreads();
  mean = red[16];
  invstd = red[17];
}

// ---- precompute: transpose many weight matrices -----------------------------
struct TPItem { const float* in; float* out; int R; int C; };
struct TPArgs { TPItem m[10]; };

__global__ __launch_bounds__(256) void transpose_many(TPArgs args) {
  const TPItem t = args.m[blockIdx.z];
  int r0 = blockIdx.x * 32, c0 = blockIdx.y * 32;
  if (r0 >= t.R || c0 >= t.C) return;
  __shared__ float tile[32][33];
  int tid = threadIdx.x;
  int i = tid >> 3, j4 = (tid & 7) * 4;
  float4 v = *(const float4*)(t.in + (size_t)(r0 + i) * t.C + c0 + j4);
  tile[i][j4] = v.x; tile[i][j4 + 1] = v.y; tile[i][j4 + 2] = v.z; tile[i][j4 + 3] = v.w;
  __syncthreads();
  float4 o;
  o.x = tile[j4][i]; o.y = tile[j4 + 1][i]; o.z = tile[j4 + 2][i]; o.w = tile[j4 + 3][i];
  *(float4*)(t.out + (size_t)(c0 + i) * t.R + r0 + j4) = o;
}

// ---- precompute: Ks,Kc -> [b][d][n] transposed ------------------------------
__global__ __launch_bounds__(256) void transpose_kv(const float* __restrict__ Ks,
                                                    const float* __restrict__ Kc,
                                                    float* __restrict__ KsT,
                                                    float* __restrict__ KcT) {
  int z = blockIdx.z;
  int b = z >> 1;
  const float* in = ((z & 1) ? Kc : Ks) + (size_t)b * NN * DD;
  float* out = ((z & 1) ? KcT : KsT) + (size_t)b * NN * DD;
  int r0 = blockIdx.x * 32, c0 = blockIdx.y * 32;  // r over n(256), c over d(512)
  __shared__ float tile[32][33];
  int tid = threadIdx.x;
  int i = tid >> 3, j4 = (tid & 7) * 4;
  float4 v = *(const float4*)(in + (size_t)(r0 + i) * DD + c0 + j4);
  tile[i][j4] = v.x; tile[i][j4 + 1] = v.y; tile[i][j4 + 2] = v.z; tile[i][j4 + 3] = v.w;
  __syncthreads();
  float4 o;
  o.x = tile[j4][i]; o.y = tile[j4 + 1][i]; o.z = tile[j4 + 2][i]; o.w = tile[j4 + 3][i];
  *(float4*)(out + (size_t)(c0 + i) * NN + r0 + j4) = o;
}

// ---- precompute: xcur = H_v0_init + pe[0] -----------------------------------
__global__ __launch_bounds__(256) void init_x(const float* __restrict__ hv0,
                                              const float* __restrict__ pe,
                                              float* __restrict__ xcur) {
  int i = blockIdx.x * 256 + threadIdx.x;  // 16384 total
  xcur[i] = hv0[i] + pe[i & (DD - 1)];
}

// ---- precompute: the 4 big K/V GEMMs (M=8192, N=4x512, K=512) ---------------
// C = A @ W.T + bias. 128x128x8 tile, 8x8 microtile.
__global__ __launch_bounds__(256) void gemm_kv(
    const float* __restrict__ A,
    const float* __restrict__ W0, const float* __restrict__ W1_,
    const float* __restrict__ W2_, const float* __restrict__ W3_,
    const float* __restrict__ b0, const float* __restrict__ b1_,
    const float* __restrict__ b2_, const float* __restrict__ b3_,
    float* __restrict__ O0, float* __restrict__ O1,
    float* __restrict__ O2, float* __restrict__ O3) {
  __shared__ __align__(16) float As[8][128];
  __shared__ __align__(16) float Bs[8][128];
  int tid = threadIdx.x;
  int bx = blockIdx.x, by = blockIdx.y;
  int mm = bx >> 2;
  int col0 = (bx & 3) * 128;
  const float* W = mm == 0 ? W0 : mm == 1 ? W1_ : mm == 2 ? W2_ : W3_;
  const float* bias = mm == 0 ? b0 : mm == 1 ? b1_ : mm == 2 ? b2_ : b3_;
  float* O = mm == 0 ? O0 : mm == 1 ? O1 : mm == 2 ? O2 : O3;
  int tx = tid & 15, ty = tid >> 4;
  int m0 = by * 128;
  int lr = tid >> 1, lk = (tid & 1) * 4;
  const float* Ap = A + (size_t)(m0 + lr) * DD + lk;
  const float* Wp = W + (size_t)(col0 + lr) * DD + lk;
  float c[8][8] = {};
  for (int k0 = 0; k0 < DD; k0 += 8) {
    float4 av = *(const float4*)(Ap + k0);
    float4 wv = *(const float4*)(Wp + k0);
    __syncthreads();
    As[lk + 0][lr] = av.x; As[lk + 1][lr] = av.y; As[lk + 2][lr] = av.z; As[lk + 3][lr] = av.w;
    Bs[lk + 0][lr] = wv.x; Bs[lk + 1][lr] = wv.y; Bs[lk + 2][lr] = wv.z; Bs[lk + 3][lr] = wv.w;
    __syncthreads();
    #pragma unroll
    for (int k = 0; k < 8; k++) {
      float a[8], bb[8];
      *(float4*)&a[0] = *(const float4*)&As[k][ty * 8];
      *(float4*)&a[4] = *(const float4*)&As[k][ty * 8 + 4];
      *(float4*)&bb[0] = *(const float4*)&Bs[k][tx * 8];
      *(float4*)&bb[4] = *(const float4*)&Bs[k][tx * 8 + 4];
      #pragma unroll
      for (int i = 0; i < 8; i++)
        #pragma unroll
        for (int j = 0; j < 8; j++) c[i][j] += a[i] * bb[j];
    }
  }
  const float* bp = bias + col0 + tx * 8;
  for (int i = 0; i < 8; i++) {
    int row = m0 + ty * 8 + i;
    float* op = O + (size_t)row * DD + col0 + tx * 8;
    #pragma unroll
    for (int jq = 0; jq < 8; jq += 4) {
      float4 v;
      v.x = c[i][jq + 0] + bp[jq + 0];
      v.y = c[i][jq + 1] + bp[jq + 1];
      v.z = c[i][jq + 2] + bp[jq + 2];
      v.w = c[i][jq + 3] + bp[jq + 3];
      *(float4*)(op + jq) = v;
    }
  }
}

// ---- per-step K1: 4 projections of xcur (q_self, k_t, v_t, q_spatial) -------
// grid (8 j-blocks, 4 b-groups), 256 thr; transposed weights, coalesced.
__global__ __launch_bounds__(256) void proj4(
    const float* __restrict__ wt8, const float* __restrict__ xcur,
    const float* __restrict__ sa_bq, const float* __restrict__ sa_bk,
    const float* __restrict__ sa_bv, const float* __restrict__ s_bq,
    float* __restrict__ qsa, float* __restrict__ Ksa,
    float* __restrict__ Vsa, float* __restrict__ qs, int t) {
  __shared__ __align__(16) float xs[8][512];
  int tid = threadIdx.x, jb = blockIdx.x, bg = blockIdx.y;
  const float* xbase = xcur + (size_t)bg * 8 * DD;
  #pragma unroll
  for (int q = 0; q < 4; q++) {
    int f = q * 1024 + tid * 4;
    *(float4*)(((float*)xs) + f) = *(const float4*)(xbase + f);
  }
  __syncthreads();
  int jg = jb * 256 + tid;
  int m = jg >> 9;           // block-uniform (jb>>1)
  int col = jg & 511;
  const int wmap[4] = {0, 1, 2, 6};  // saWqT, saWkT, saWvT, sWqT
  const float* wp = wt8 + (size_t)wmap[m] * DD * DD + col;
  float acc[8] = {};
  for (int k = 0; k < DD; k += 4) {
    float w0 = wp[(size_t)(k + 0) * DD];
    float w1 = wp[(size_t)(k + 1) * DD];
    float w2 = wp[(size_t)(k + 2) * DD];
    float w3 = wp[(size_t)(k + 3) * DD];
    #pragma unroll
    for (int bi = 0; bi < 8; bi++) {
      float4 xv = *(const float4*)&xs[bi][k];
      acc[bi] += xv.x * w0 + xv.y * w1 + xv.z * w2 + xv.w * w3;
    }
  }
  const float* bptr = m == 0 ? sa_bq : m == 1 ? sa_bk : m == 2 ? sa_bv : s_bq;
  float bv = bptr[col];
  #pragma unroll
  for (int bi = 0; bi < 8; bi++) {
    int b = bg * 8 + bi;
    float v = acc[bi] + bv;
    if (m == 0)      qsa[(size_t)b * DD + col] = v;
    else if (m == 1) Ksa[((size_t)b * TT + t) * DD + col] = v;
    else if (m == 2) Vsa[((size_t)b * TT + t) * DD + col] = v;
    else             qs[(size_t)b * DD + col] = v;
  }
}

// ---- per-step K2: self-attn -> Wo -> +res -> LN1 -> ca-q -> ca-attn -> Wo ->
//      +res -> LN2 -> z, u3init.  One block per batch, 512 threads.
__global__ __launch_bounds__(512) void dec_attn(
    const float* __restrict__ qsa, const float* __restrict__ Ksa,
    const float* __restrict__ Vsa, const float* __restrict__ KcT,
    const float* __restrict__ Vc,
    const float* __restrict__ saWoT, const float* __restrict__ caWqT,
    const float* __restrict__ caWoT,
    const float* __restrict__ xcur,
    const float* __restrict__ sa_bo, const float* __restrict__ ca_bq,
    const float* __restrict__ ca_bo,
    const float* __restrict__ ln1w, const float* __restrict__ ln1b,
    const float* __restrict__ ln2w, const float* __restrict__ ln2b,
    const float* __restrict__ fb2,
    float* __restrict__ zbuf, float* __restrict__ u3, int t) {
  int b = blockIdx.x, tid = threadIdx.x;
  __shared__ __align__(16) float sQ[512];
  __shared__ __align__(16) float sAtt[512];
  __shared__ __align__(16) float sY[512];
  __shared__ float sU[512];
  __shared__ float sS[NH * 256];
  __shared__ float red[24];
  __shared__ float sInv[NH];
  int L = t + 1;

  sQ[tid] = qsa[(size_t)b * DD + tid];
  __syncthreads();

  // self scores (one (h,j) pair per thread; 8*L <= 480)
  if (tid < NH * L) {
    int h = tid / L, j = tid - h * L;
    const float* kp = Ksa + ((size_t)b * TT + j) * DD + h * DH;
    const float* qp = &sQ[h * DH];
    float a = 0.f;
    #pragma unroll
    for (int i = 0; i < DH; i += 4) {
      float4 kv = *(const float4*)(kp + i);
      a += qp[i] * kv.x + qp[i + 1] * kv.y + qp[i + 2] * kv.z + qp[i + 3] * kv.w;
    }
    sS[h * 64 + j] = a * 0.125f;
  }
  __syncthreads();
  if (tid < NH) {  // tiny softmax over <=60 keys
    float mx = -1e30f;
    for (int j = 0; j < L; j++) mx = fmaxf(mx, sS[tid * 64 + j]);
    float s = 0.f;
    for (int j = 0; j < L; j++) {
      float e = __expf(sS[tid * 64 + j] - mx);
      sS[tid * 64 + j] = e;
      s += e;
    }
    sInv[tid] = 1.f / s;
  }
  __syncthreads();
  {  // PV
    int h = tid >> 6;
    const float* vp = Vsa + (size_t)b * TT * DD + tid;
    float a = 0.f;
    for (int j = 0; j < L; j++) a += sS[h * 64 + j] * vp[(size_t)j * DD];
    sAtt[tid] = a * sInv[h];
  }
  __syncthreads();
  float mean, inv;
  {  // Wo proj + residual + LN1
    const float* wp = saWoT + tid;
    float a = 0.f;
    for (int k = 0; k < DD; k += 4) {
      float4 s4 = *(const float4*)&sAtt[k];
      a += s4.x * wp[(size_t)(k + 0) * DD] + s4.y * wp[(size_t)(k + 1) * DD] +
           s4.z * wp[(size_t)(k + 2) * DD] + s4.w * wp[(size_t)(k + 3) * DD];
    }
    float u1 = a + sa_bo[tid] + xcur[(size_t)b * DD + tid];
    sU[tid] = u1;
    ln_stats512(u1, red, tid, mean, inv);
    sY[tid] = (u1 - mean) * inv * ln1w[tid] + ln1b[tid];
  }
  __syncthreads();
  {  // cross-attn q projection (reuse sQ)
    const float* wp = caWqT + tid;
    float a = 0.f;
    for (int k = 0; k < DD; k += 4) {
      float4 s4 = *(const float4*)&sY[k];
      a += s4.x * wp[(size_t)(k + 0) * DD] + s4.y * wp[(size_t)(k + 1) * DD] +
           s4.z * wp[(size_t)(k + 2) * DD] + s4.w * wp[(size_t)(k + 3) * DD];
    }
    sQ[tid] = a + ca_bq[tid];
  }
  __syncthreads();
  {  // ca scores via transposed Kc (coalesced over n)
    int n = tid & 255, hg = tid >> 8;
    for (int h = hg * 4; h < hg * 4 + 4; h++) {
      const float* kp = KcT + (size_t)b * NN * DD + (size_t)(h * DH) * NN + n;
      float a = 0.f;
      #pragma unroll 4
      for (int i = 0; i < DH; i++) a += sQ[h * DH + i] * kp[(size_t)i * NN];
      sS[h * 256 + n] = a * 0.125f;
    }
  }
  __syncthreads();
  {  // softmax: wave h handles head h (4 keys per lane)
    int h = tid >> 6, l = tid & 63;
    float v0 = sS[h * 256 + l],       v1 = sS[h * 256 + 64 + l];
    float v2 = sS[h * 256 + 128 + l], v3 = sS[h * 256 + 192 + l];
    float m4 = fmaxf(fmaxf(v0, v1), fmaxf(v2, v3));
    #pragma unroll
    for (int m = 32; m >= 1; m >>= 1) m4 = fmaxf(m4, __shfl_xor(m4, m));
    v0 = __expf(v0 - m4); v1 = __expf(v1 - m4);
    v2 = __expf(v2 - m4); v3 = __expf(v3 - m4);
    sS[h * 256 + l] = v0; sS[h * 256 + 64 + l] = v1;
    sS[h * 256 + 128 + l] = v2; sS[h * 256 + 192 + l] = v3;
    float s4 = v0 + v1 + v2 + v3;
    #pragma unroll
    for (int m = 32; m >= 1; m >>= 1) s4 += __shfl_xor(s4, m);
    if (l == 0) sInv[h] = 1.f / s4;
  }
  __syncthreads();
  {  // PV
    int h = tid >> 6;
    const float* vp = Vc + (size_t)b * NN * DD + tid;
    float a = 0.f;
    #pragma unroll 4
    for (int n = 0; n < NN; n++) a += sS[h * 256 + n] * vp[(size_t)n * DD];
    sAtt[tid] = a * sInv[h];
  }
  __syncthreads();
  {  // ca Wo proj + residual + LN2 -> z, u3 = z + b2
    const float* wp = caWoT + tid;
    float a = 0.f;
    for (int k = 0; k < DD; k += 4) {
      float4 s4 = *(const float4*)&sAtt[k];
      a += s4.x * wp[(size_t)(k + 0) * DD] + s4.y * wp[(size_t)(k + 1) * DD] +
           s4.z * wp[(size_t)(k + 2) * DD] + s4.w * wp[(size_t)(k + 3) * DD];
    }
    float u2 = a + ca_bo[tid] + sY[tid];
    float mean2, inv2;
    ln_stats512(u2, red, tid, mean2, inv2);
    float z = (u2 - mean2) * inv2 * ln2w[tid] + ln2b[tid];
    zbuf[(size_t)b * DD + tid] = z;
    u3[(size_t)b * DD + tid] = z + fb2[tid];
  }
}

// ---- per-step K3: FFN layer 1 (relu) ---------------------------------------
__global__ __launch_bounds__(256) void ffn1(
    const float* __restrict__ W1t, const float* __restrict__ b1,
    const float* __restrict__ zbuf, float* __restrict__ hbuf) {
  __shared__ __align__(16) float xs[8][512];
  int tid = threadIdx.x, jb = blockIdx.x, bg = blockIdx.y;
  const float* xbase = zbuf + (size_t)bg * 8 * DD;
  #pragma unroll
  for (int q = 0; q < 4; q++) {
    int f = q * 1024 + tid * 4;
    *(float4*)(((float*)xs) + f) = *(const float4*)(xbase + f);
  }
  __syncthreads();
  int col = jb * 256 + tid;  // [0, 2048)
  const float* wp = W1t + col;
  float acc[8] = {};
  for (int k = 0; k < DD; k += 4) {
    float w0 = wp[(size_t)(k + 0) * DF];
    float w1 = wp[(size_t)(k + 1) * DF];
    float w2 = wp[(size_t)(k + 2) * DF];
    float w3 = wp[(size_t)(k + 3) * DF];
    #pragma unroll
    for (int bi = 0; bi < 8; bi++) {
      float4 xv = *(const float4*)&xs[bi][k];
      acc[bi] += xv.x * w0 + xv.y * w1 + xv.z * w2 + xv.w * w3;
    }
  }
  float bb = b1[col];
  #pragma unroll
  for (int bi = 0; bi < 8; bi++)
    hbuf[(size_t)(bg * 8 + bi) * DF + col] = fmaxf(acc[bi] + bb, 0.f);
}

// ---- per-step K4: FFN layer 2, split-k x4, atomics into u3 ------------------
__global__ __launch_bounds__(256) void ffn2(
    const float* __restrict__ W2t, const float* __restrict__ hbuf,
    float* __restrict__ u3) {
  __shared__ __align__(16) float hs[8][512];
  int tid = threadIdx.x, jb = blockIdx.x, bg = blockIdx.y, ks = blockIdx.z;
  int k0 = ks * 512;
  const float* hbase = hbuf + (size_t)bg * 8 * DF + k0;
  #pragma unroll
  for (int q = 0; q < 4; q++) {
    int f = q * 1024 + tid * 4;
    int r = f >> 9, c = f & 511;
    *(float4*)&hs[r][c] = *(const float4*)(hbase + (size_t)r * DF + c);
  }
  __syncthreads();
  int col = jb * 256 + tid;  // [0, 512)
  const float* wp = W2t + (size_t)k0 * DD + col;
  float acc[8] = {};
  for (int k = 0; k < 512; k += 4) {
    float w0 = wp[(size_t)(k + 0) * DD];
    float w1 = wp[(size_t)(k + 1) * DD];
    float w2 = wp[(size_t)(k + 2) * DD];
    float w3 = wp[(size_t)(k + 3) * DD];
    #pragma unroll
    for (int bi = 0; bi < 8; bi++) {
      float4 hv = *(const float4*)&hs[bi][k];
      acc[bi] += hv.x * w0 + hv.y * w1 + hv.z * w2 + hv.w * w3;
    }
  }
  #pragma unroll
  for (int bi = 0; bi < 8; bi++)
    atomicAdd(&u3[(size_t)(bg * 8 + bi) * DD + col], acc[bi]);
}

// ---- per-step K5: spatial attn + Wo + LN3(u3) + nxt + xnext + out proj ------
__global__ __launch_bounds__(512) void spatial_out(
    const float* __restrict__ qs, const float* __restrict__ KsT,
    const float* __restrict__ Vs, const float* __restrict__ sWoT,
    const float* __restrict__ s_bo, const float* __restrict__ u3,
    const float* __restrict__ ln3w, const float* __restrict__ ln3b,
    const float* __restrict__ pe, const float* __restrict__ Wout,
    const float* __restrict__ bout, float* __restrict__ xcur,
    float* __restrict__ out, int t) {
  int b = blockIdx.x, tid = threadIdx.x;
  __shared__ __align__(16) float sQ[512];
  __shared__ __align__(16) float sAtt[512];
  __shared__ float sN[512];
  __shared__ float sS[NH * 256];
  __shared__ float red[24];
  __shared__ float sInv[NH];

  sQ[tid] = qs[(size_t)b * DD + tid];
  __syncthreads();
  {  // scores via KsT
    int n = tid & 255, hg = tid >> 8;
    for (int h = hg * 4; h < hg * 4 + 4; h++) {
      const float* kp = KsT + (size_t)b * NN * DD + (size_t)(h * DH) * NN + n;
      float a = 0.f;
      #pragma unroll 4
      for (int i = 0; i < DH; i++) a += sQ[h * DH + i] * kp[(size_t)i * NN];
      sS[h * 256 + n] = a * 0.125f;
    }
  }
  __syncthreads();
  {  // softmax per head (wave h)
    int h = tid >> 6, l = tid & 63;
    float v0 = sS[h * 256 + l],       v1 = sS[h * 256 + 64 + l];
    float v2 = sS[h * 256 + 128 + l], v3 = sS[h * 256 + 192 + l];
    float m4 = fmaxf(fmaxf(v0, v1), fmaxf(v2, v3));
    #pragma unroll
    for (int m = 32; m >= 1; m >>= 1) m4 = fmaxf(m4, __shfl_xor(m4, m));
    v0 = __expf(v0 - m4); v1 = __expf(v1 - m4);
    v2 = __expf(v2 - m4); v3 = __expf(v3 - m4);
    sS[h * 256 + l] = v0; sS[h * 256 + 64 + l] = v1;
    sS[h * 256 + 128 + l] = v2; sS[h * 256 + 192 + l] = v3;
    float s4 = v0 + v1 + v2 + v3;
    #pragma unroll
    for (int m = 32; m >= 1; m >>= 1) s4 += __shfl_xor(s4, m);
    if (l == 0) sInv[h] = 1.f / s4;
  }
  __syncthreads();
  {  // PV
    int h = tid >> 6;
    const float* vp = Vs + (size_t)b * NN * DD + tid;
    float a = 0.f;
    #pragma unroll 4
    for (int n = 0; n < NN; n++) a += sS[h * 256 + n] * vp[(size_t)n * DD];
    sAtt[tid] = a * sInv[h];
  }
  __syncthreads();
  {  // ctx proj + LN3 + nxt + xnext
    const float* wp = sWoT + tid;
    float a = 0.f;
    for (int k = 0; k < DD; k += 4) {
      float4 s4 = *(const float4*)&sAtt[k];
      a += s4.x * wp[(size_t)(k + 0) * DD] + s4.y * wp[(size_t)(k + 1) * DD] +
           s4.z * wp[(size_t)(k + 2) * DD] + s4.w * wp[(size_t)(k + 3) * DD];
    }
    float ctx = a + s_bo[tid];
    float u = u3[(size_t)b * DD + tid];
    float mean, inv;
    ln_stats512(u, red, tid, mean, inv);
    float w = (u - mean) * inv * ln3w[tid] + ln3b[tid];
    float nxt = w + ctx;
    sN[tid] = nxt;
    float xn = nxt + (t < TT - 1 ? pe[(size_t)(t + 1) * DD + tid] : 0.f);
    xcur[(size_t)b * DD + tid] = xn;
  }
  __syncthreads();
  if (tid < 128) {  // out[b, t, c] = nxt . Wout[c] + bout[c]
    int c = tid >> 6, l = tid & 63;
    const float* wo = Wout + (size_t)c * DD;
    float a = 0.f;
    #pragma unroll
    for (int i = 0; i < DD / 64; i++) a += sN[l + i * 64] * wo[l + i * 64];
    #pragma unroll
    for (int m = 32; m >= 1; m >>= 1) a += __shfl_xor(a, m);
    if (l == 0) out[((size_t)b * TT + t) * 2 + c] = a + bout[c];
  }
}

// ---------------------------------------------------------------------------
extern "C" void kernel_launch(void* const* d_in, const int* in_sizes, int n_in,
                              void* d_out, int out_size, void* d_ws, size_t ws_size,
                              hipStream_t stream) {
  const float* H_v_all = (const float*)d_in[0];
  const float* H_v0    = (const float*)d_in[1];
  const float* pe      = (const float*)d_in[2];
  const float* s_Wq = (const float*)d_in[3];
  const float* s_Wk = (const float*)d_in[4];
  const float* s_Wv = (const float*)d_in[5];
  const float* s_Wo = (const float*)d_in[6];
  const float* s_bq = (const float*)d_in[7];
  const float* s_bk = (const float*)d_in[8];
  const float* s_bv = (const float*)d_in[9];
  const float* s_bo = (const float*)d_in[10];
  const float* sa_Wq = (const float*)d_in[11];
  const float* sa_Wk = (const float*)d_in[12];
  const float* sa_Wv = (const float*)d_in[13];
  const float* sa_Wo = (const float*)d_in[14];
  const float* sa_bq = (const float*)d_in[15];
  const float* sa_bk = (const float*)d_in[16];
  const float* sa_bv = (const float*)d_in[17];
  const float* sa_bo = (const float*)d_in[18];
  const float* ca_Wq = (const float*)d_in[19];
  const float* ca_Wk = (const float*)d_in[20];
  const float* ca_Wv = (const float*)d_in[21];
  const float* ca_Wo = (const float*)d_in[22];
  const float* ca_bq = (const float*)d_in[23];
  const float* ca_bk = (const float*)d_in[24];
  const float* ca_bv = (const float*)d_in[25];
  const float* ca_bo = (const float*)d_in[26];
  const float* ln1w = (const float*)d_in[27];
  const float* ln1b = (const float*)d_in[28];
  const float* ln2w = (const float*)d_in[29];
  const float* ln2b = (const float*)d_in[30];
  const float* ln3w = (const float*)d_in[31];
  const float* ln3b = (const float*)d_in[32];
  const float* W1   = (const float*)d_in[33];
  const float* b1   = (const float*)d_in[34];
  const float* W2   = (const float*)d_in[35];
  const float* b2   = (const float*)d_in[36];
  const float* Wout = (const float*)d_in[37];
  const float* bout = (const float*)d_in[38];

  float* ws  = (float*)d_ws;
  float* Ks  = ws + OFF_KS;
  float* Vs  = ws + OFF_VS;
  float* Kc  = ws + OFF_KC;
  float* Vc  = ws + OFF_VC;
  float* KsT = ws + OFF_KST;
  float* KcT = ws + OFF_KCT;
  float* Ksa = ws + OFF_KSA;
  float* Vsa = ws + OFF_VSA;
  float* wt8 = ws + OFF_WT;
  float* W1t = ws + OFF_W1T;
  float* W2t = ws + OFF_W2T;
  float* xcur = ws + OFF_X;
  float* qsa  = ws + OFF_QSA;
  float* qsb  = ws + OFF_QS;
  float* zbuf = ws + OFF_Z;
  float* u3   = ws + OFF_U3;
  float* hbuf = ws + OFF_H;
  float* out  = (float*)d_out;

  // --- precompute -----------------------------------------------------------
  TPArgs tp;
  tp.m[0] = {sa_Wq, wt8 + 0ull * DD * DD, DD, DD};
  tp.m[1] = {sa_Wk, wt8 + 1ull * DD * DD, DD, DD};
  tp.m[2] = {sa_Wv, wt8 + 2ull * DD * DD, DD, DD};
  tp.m[3] = {sa_Wo, wt8 + 3ull * DD * DD, DD, DD};
  tp.m[4] = {ca_Wq, wt8 + 4ull * DD * DD, DD, DD};
  tp.m[5] = {ca_Wo, wt8 + 5ull * DD * DD, DD, DD};
  tp.m[6] = {s_Wq,  wt8 + 6ull * DD * DD, DD, DD};
  tp.m[7] = {s_Wo,  wt8 + 7ull * DD * DD, DD, DD};
  tp.m[8] = {W1, W1t, DF, DD};   // -> W1t[512][2048]
  tp.m[9] = {W2, W2t, DD, DF};   // -> W2t[2048][512]
  hipLaunchKernelGGL(transpose_many, dim3(64, 64, 10), dim3(256), 0, stream, tp);

  hipLaunchKernelGGL(gemm_kv, dim3(16, 64), dim3(256), 0, stream,
                     H_v_all, s_Wk, s_Wv, ca_Wk, ca_Wv,
                     s_bk, s_bv, ca_bk, ca_bv, Ks, Vs, Kc, Vc);

  hipLaunchKernelGGL(transpose_kv, dim3(8, 16, 64), dim3(256), 0, stream,
                     Ks, Kc, KsT, KcT);

  hipLaunchKernelGGL(init_x, dim3(64), dim3(256), 0, stream, H_v0, pe, xcur);

  // --- sequential decode ----------------------------------------------------
  for (int t = 0; t < TT; t++) {
    hipLaunchKernelGGL(proj4, dim3(8, 4), dim3(256), 0, stream,
                       wt8, xcur, sa_bq, sa_bk, sa_bv, s_bq,
                       qsa, Ksa, Vsa, qsb, t);
    hipLaunchKernelGGL(dec_attn, dim3(NB), dim3(512), 0, stream,
                       qsa, Ksa, Vsa, KcT, Vc,
                       wt8 + 3ull * DD * DD, wt8 + 4ull * DD * DD, wt8 + 5ull * DD * DD,
                       xcur, sa_bo, ca_bq, ca_bo,
                       ln1w, ln1b, ln2w, ln2b, b2, zbuf, u3, t);
    hipLaunchKernelGGL(ffn1, dim3(8, 4), dim3(256), 0, stream, W1t, b1, zbuf, hbuf);
    hipLaunchKernelGGL(ffn2, dim3(2, 4, 4), dim3(256), 0, stream, W2t, hbuf, u3);
    hipLaunchKernelGGL(spatial_out, dim3(NB), dim3(512), 0, stream,
                       qsb, KsT, Vs, wt8 + 7ull * DD * DD, s_bo, u3,
                       ln3w, ln3b, pe, Wout, bout, xcur, out, t);
  }
}

// Round 2
// 14399.373 us; speedup vs baseline: 1.0279x; 1.0279x over previous
//
#include <hip/hip_runtime.h>

// ---------------------------------------------------------------------------
// VehicleTrajectoryDecoder: B=32, N=256, D=512, H=8 (dh=64), T=60, DFF=2048.
// R2: restructure per-step work so no block reads >0.5MB of weights
// (per-CU L2 bw ~150 GB/s was the R1 bottleneck: one-block-per-batch kernels
// streamed 3MB/CU => ~25us each). Attention now per-(b,h) (256 blocks),
// GEMVs col x batch-group sliced, LayerNorms fused into consumer prologues.
// 9 kernels/step, each ~2-4us of work.
// ---------------------------------------------------------------------------

#define NB 32
#define NN 256
#define DD 512
#define NH 8
#define DH 64
#define TT 60
#define DF 2048

// ---- workspace layout (floats) --------------------------------------------
constexpr size_t SZ_KV  = (size_t)NB * NN * DD;        // 4194304
constexpr size_t SZ_SA  = (size_t)NB * TT * DD;        // 983040
constexpr size_t SZ_ROW = (size_t)NB * DD;             // 16384
constexpr size_t OFF_KS  = 0;
constexpr size_t OFF_VS  = OFF_KS  + SZ_KV;
constexpr size_t OFF_KC  = OFF_VS  + SZ_KV;
constexpr size_t OFF_VC  = OFF_KC  + SZ_KV;
constexpr size_t OFF_KST = OFF_VC  + SZ_KV;            // Ks transposed [b][d][n]
constexpr size_t OFF_KCT = OFF_KST + SZ_KV;            // Kc transposed [b][d][n]
constexpr size_t OFF_KSA = OFF_KCT + SZ_KV;            // self-attn K cache [b][t][d]
constexpr size_t OFF_VSA = OFF_KSA + SZ_SA;
constexpr size_t OFF_WT  = OFF_VSA + SZ_SA;            // 8 transposed 512x512 weights
constexpr size_t OFF_W1T = OFF_WT  + 8ull * DD * DD;   // [512][2048]
constexpr size_t OFF_W2T = OFF_W1T + (size_t)DD * DF;  // [2048][512]
constexpr size_t OFF_X   = OFF_W2T + (size_t)DF * DD;  // xcur [32][512]
constexpr size_t OFF_QSA = OFF_X   + SZ_ROW;
constexpr size_t OFF_QS  = OFF_QSA + SZ_ROW;
constexpr size_t OFF_ASA = OFF_QS  + SZ_ROW;  // self-attn out
constexpr size_t OFF_ASP = OFF_ASA + SZ_ROW;  // spatial-attn out
constexpr size_t OFF_ACA = OFF_ASP + SZ_ROW;  // cross-attn out
constexpr size_t OFF_U1  = OFF_ACA + SZ_ROW;
constexpr size_t OFF_Y1  = OFF_U1  + SZ_ROW;
constexpr size_t OFF_QC  = OFF_Y1  + SZ_ROW;
constexpr size_t OFF_U2  = OFF_QC  + SZ_ROW;
constexpr size_t OFF_CTX = OFF_U2  + SZ_ROW;
constexpr size_t OFF_U3  = OFF_CTX + SZ_ROW;
constexpr size_t OFF_H   = OFF_U3  + SZ_ROW;  // hbuf [32][2048]
// end ~= 126.2 MB

// ---- helpers ----------------------------------------------------------------
__device__ __forceinline__ void ln_stats512(float v, float* red, int tid,
                                            float& mean, float& invstd) {
  float s = v, q = v * v;
  #pragma unroll
  for (int m = 32; m >= 1; m >>= 1) { s += __shfl_xor(s, m); q += __shfl_xor(q, m); }
  if ((tid & 63) == 0) { red[tid >> 6] = s; red[8 + (tid >> 6)] = q; }
  __syncthreads();
  if (tid == 0) {
    float ss = 0.f, qq = 0.f;
    #pragma unroll
    for (int i = 0; i < 8; i++) { ss += red[i]; qq += red[8 + i]; }
    float m_ = ss * (1.0f / 512.0f);
    float var = qq * (1.0f / 512.0f) - m_ * m_;
    red[16] = m_;
    red[17] = rsqrtf(var + 1e-5f);
  }
  __syncthreads();
  mean = red[16];
  invstd = red[17];
}

// LN stats for 8 LDS-resident rows of 512, 256-thread block.
// wave w handles rows 2w, 2w+1 (wave-local reduce, no cross-wave step).
__device__ __forceinline__ void ln8_256(const float (*xs)[DD], float* lm,
                                        float* li, int tid) {
  int w = tid >> 6, lane = tid & 63;
  #pragma unroll
  for (int rr = 0; rr < 2; rr++) {
    int r = w * 2 + rr;
    float s = 0.f, q = 0.f;
    #pragma unroll
    for (int i = 0; i < 8; i++) {
      float v = xs[r][lane + i * 64];
      s += v; q += v * v;
    }
    #pragma unroll
    for (int m = 32; m >= 1; m >>= 1) { s += __shfl_xor(s, m); q += __shfl_xor(q, m); }
    if (lane == 0) {
      float mm = s * (1.0f / 512.0f);
      lm[r] = mm;
      li[r] = rsqrtf(q * (1.0f / 512.0f) - mm * mm + 1e-5f);
    }
  }
  __syncthreads();
}

// attention over 256 keys for one (b,h), 256-thread block.
// KT is [d][n] layout base for this b; V is [n][512] base for this b.
__device__ __forceinline__ void attn_n256(
    const float* __restrict__ qrow, int h,
    const float* __restrict__ KT, const float* __restrict__ V,
    float* __restrict__ outrow,
    float* sQh, float* sP, float* sB, float* redM, float* redS, int tid) {
  int w = tid >> 6, lane = tid & 63;
  if (tid < DH) sQh[tid] = qrow[h * DH + tid];
  __syncthreads();
  const float* kp = KT + (size_t)(h * DH) * NN + tid;
  float a = 0.f;
  #pragma unroll 8
  for (int i = 0; i < DH; i++) a += sQh[i] * kp[(size_t)i * NN];
  a *= 0.125f;
  float m = a;
  #pragma unroll
  for (int s = 32; s >= 1; s >>= 1) m = fmaxf(m, __shfl_xor(m, s));
  if (lane == 0) redM[w] = m;
  __syncthreads();
  m = fmaxf(fmaxf(redM[0], redM[1]), fmaxf(redM[2], redM[3]));
  float e = __expf(a - m);
  float ss = e;
  #pragma unroll
  for (int s = 32; s >= 1; s >>= 1) ss += __shfl_xor(ss, s);
  if (lane == 0) redS[w] = ss;
  sP[tid] = e;
  __syncthreads();
  float inv = 1.f / (redS[0] + redS[1] + redS[2] + redS[3]);
  int q4 = tid >> 6, d = tid & 63;
  const float* vp = V + (size_t)(q4 * 64) * DD + h * DH + d;
  float acc = 0.f;
  #pragma unroll 4
  for (int n = 0; n < 64; n++) acc += sP[q4 * 64 + n] * vp[(size_t)n * DD];
  sB[tid] = acc;
  __syncthreads();
  if (tid < 64) {
    float o = (sB[tid] + sB[64 + tid] + sB[128 + tid] + sB[192 + tid]) * inv;
    outrow[h * DH + tid] = o;
  }
}

// ---- precompute: transpose many weight matrices -----------------------------
struct TPItem { const float* in; float* out; int R; int C; };
struct TPArgs { TPItem m[10]; };

__global__ __launch_bounds__(256) void transpose_many(TPArgs args) {
  const TPItem t = args.m[blockIdx.z];
  int r0 = blockIdx.x * 32, c0 = blockIdx.y * 32;
  if (r0 >= t.R || c0 >= t.C) return;
  __shared__ float tile[32][33];
  int tid = threadIdx.x;
  int i = tid >> 3, j4 = (tid & 7) * 4;
  float4 v = *(const float4*)(t.in + (size_t)(r0 + i) * t.C + c0 + j4);
  tile[i][j4] = v.x; tile[i][j4 + 1] = v.y; tile[i][j4 + 2] = v.z; tile[i][j4 + 3] = v.w;
  __syncthreads();
  float4 o;
  o.x = tile[j4][i]; o.y = tile[j4 + 1][i]; o.z = tile[j4 + 2][i]; o.w = tile[j4 + 3][i];
  *(float4*)(t.out + (size_t)(c0 + i) * t.R + r0 + j4) = o;
}

// ---- precompute: Ks,Kc -> [b][d][n] transposed ------------------------------
__global__ __launch_bounds__(256) void transpose_kv(const float* __restrict__ Ks,
                                                    const float* __restrict__ Kc,
                                                    float* __restrict__ KsT,
                                                    float* __restrict__ KcT) {
  int z = blockIdx.z;
  int b = z >> 1;
  const float* in = ((z & 1) ? Kc : Ks) + (size_t)b * NN * DD;
  float* out = ((z & 1) ? KcT : KsT) + (size_t)b * NN * DD;
  int r0 = blockIdx.x * 32, c0 = blockIdx.y * 32;
  __shared__ float tile[32][33];
  int tid = threadIdx.x;
  int i = tid >> 3, j4 = (tid & 7) * 4;
  float4 v = *(const float4*)(in + (size_t)(r0 + i) * DD + c0 + j4);
  tile[i][j4] = v.x; tile[i][j4 + 1] = v.y; tile[i][j4 + 2] = v.z; tile[i][j4 + 3] = v.w;
  __syncthreads();
  float4 o;
  o.x = tile[j4][i]; o.y = tile[j4 + 1][i]; o.z = tile[j4 + 2][i]; o.w = tile[j4 + 3][i];
  *(float4*)(out + (size_t)(c0 + i) * NN + r0 + j4) = o;
}

// ---- precompute: xcur = H_v0_init + pe[0] -----------------------------------
__global__ __launch_bounds__(256) void init_x(const float* __restrict__ hv0,
                                              const float* __restrict__ pe,
                                              float* __restrict__ xcur) {
  int i = blockIdx.x * 256 + threadIdx.x;
  xcur[i] = hv0[i] + pe[i & (DD - 1)];
}

// ---- precompute: the 4 big K/V GEMMs (M=8192, N=4x512, K=512) ---------------
__global__ __launch_bounds__(256) void gemm_kv(
    const float* __restrict__ A,
    const float* __restrict__ W0, const float* __restrict__ W1_,
    const float* __restrict__ W2_, const float* __restrict__ W3_,
    const float* __restrict__ b0, const float* __restrict__ b1_,
    const float* __restrict__ b2_, const float* __restrict__ b3_,
    float* __restrict__ O0, float* __restrict__ O1,
    float* __restrict__ O2, float* __restrict__ O3) {
  __shared__ __align__(16) float As[8][128];
  __shared__ __align__(16) float Bs[8][128];
  int tid = threadIdx.x;
  int bx = blockIdx.x, by = blockIdx.y;
  int mm = bx >> 2;
  int col0 = (bx & 3) * 128;
  const float* W = mm == 0 ? W0 : mm == 1 ? W1_ : mm == 2 ? W2_ : W3_;
  const float* bias = mm == 0 ? b0 : mm == 1 ? b1_ : mm == 2 ? b2_ : b3_;
  float* O = mm == 0 ? O0 : mm == 1 ? O1 : mm == 2 ? O2 : O3;
  int tx = tid & 15, ty = tid >> 4;
  int m0 = by * 128;
  int lr = tid >> 1, lk = (tid & 1) * 4;
  const float* Ap = A + (size_t)(m0 + lr) * DD + lk;
  const float* Wp = W + (size_t)(col0 + lr) * DD + lk;
  float c[8][8] = {};
  for (int k0 = 0; k0 < DD; k0 += 8) {
    float4 av = *(const float4*)(Ap + k0);
    float4 wv = *(const float4*)(Wp + k0);
    __syncthreads();
    As[lk + 0][lr] = av.x; As[lk + 1][lr] = av.y; As[lk + 2][lr] = av.z; As[lk + 3][lr] = av.w;
    Bs[lk + 0][lr] = wv.x; Bs[lk + 1][lr] = wv.y; Bs[lk + 2][lr] = wv.z; Bs[lk + 3][lr] = wv.w;
    __syncthreads();
    #pragma unroll
    for (int k = 0; k < 8; k++) {
      float a[8], bb[8];
      *(float4*)&a[0] = *(const float4*)&As[k][ty * 8];
      *(float4*)&a[4] = *(const float4*)&As[k][ty * 8 + 4];
      *(float4*)&bb[0] = *(const float4*)&Bs[k][tx * 8];
      *(float4*)&bb[4] = *(const float4*)&Bs[k][tx * 8 + 4];
      #pragma unroll
      for (int i = 0; i < 8; i++)
        #pragma unroll
        for (int j = 0; j < 8; j++) c[i][j] += a[i] * bb[j];
    }
  }
  const float* bp = bias + col0 + tx * 8;
  for (int i = 0; i < 8; i++) {
    int row = m0 + ty * 8 + i;
    float* op = O + (size_t)row * DD + col0 + tx * 8;
    #pragma unroll
    for (int jq = 0; jq < 8; jq += 4) {
      float4 v;
      v.x = c[i][jq + 0] + bp[jq + 0];
      v.y = c[i][jq + 1] + bp[jq + 1];
      v.z = c[i][jq + 2] + bp[jq + 2];
      v.w = c[i][jq + 3] + bp[jq + 3];
      *(float4*)(op + jq) = v;
    }
  }
}

// ---- K1: 4 projections of xcur (q_self, k_t, v_t, q_spatial) ----------------
__global__ __launch_bounds__(256) void proj4(
    const float* __restrict__ wt8, const float* __restrict__ xcur,
    const float* __restrict__ sa_bq, const float* __restrict__ sa_bk,
    const float* __restrict__ sa_bv, const float* __restrict__ s_bq,
    float* __restrict__ qsa, float* __restrict__ Ksa,
    float* __restrict__ Vsa, float* __restrict__ qs, int t) {
  __shared__ __align__(16) float xs[8][DD];
  int tid = threadIdx.x, jb = blockIdx.x, bg = blockIdx.y;
  const float* xbase = xcur + (size_t)bg * 8 * DD;
  #pragma unroll
  for (int q = 0; q < 4; q++) {
    int f = q * 1024 + tid * 4;
    *(float4*)(((float*)xs) + f) = *(const float4*)(xbase + f);
  }
  __syncthreads();
  int jg = jb * 256 + tid;
  int m = jg >> 9;
  int col = jg & 511;
  const int wmap[4] = {0, 1, 2, 6};  // saWqT, saWkT, saWvT, sWqT
  const float* wp = wt8 + (size_t)wmap[m] * DD * DD + col;
  float acc[8] = {};
  for (int k = 0; k < DD; k += 4) {
    float w0 = wp[(size_t)(k + 0) * DD];
    float w1 = wp[(size_t)(k + 1) * DD];
    float w2 = wp[(size_t)(k + 2) * DD];
    float w3 = wp[(size_t)(k + 3) * DD];
    #pragma unroll
    for (int bi = 0; bi < 8; bi++) {
      float4 xv = *(const float4*)&xs[bi][k];
      acc[bi] += xv.x * w0 + xv.y * w1 + xv.z * w2 + xv.w * w3;
    }
  }
  const float* bptr = m == 0 ? sa_bq : m == 1 ? sa_bk : m == 2 ? sa_bv : s_bq;
  float bv = bptr[col];
  #pragma unroll
  for (int bi = 0; bi < 8; bi++) {
    int b = bg * 8 + bi;
    float v = acc[bi] + bv;
    if (m == 0)      qsa[(size_t)b * DD + col] = v;
    else if (m == 1) Ksa[((size_t)b * TT + t) * DD + col] = v;
    else if (m == 2) Vsa[((size_t)b * TT + t) * DD + col] = v;
    else             qs[(size_t)b * DD + col] = v;
  }
}

// ---- K2: self-attn (blocks 0..31, per b) + spatial attn (blocks 32..287,
//          per (b,h)).  256 threads. ---------------------------------------
__global__ __launch_bounds__(256) void attn_self_spatial(
    const float* __restrict__ qsa, const float* __restrict__ Ksa,
    const float* __restrict__ Vsa, const float* __restrict__ qs,
    const float* __restrict__ KsT, const float* __restrict__ Vs,
    float* __restrict__ attnSA, float* __restrict__ attnS, int t) {
  __shared__ float sQ[DD];
  __shared__ float sP[DD];
  __shared__ float sB[256];
  __shared__ float redM[4], redS[4], sInv[NH];
  int tid = threadIdx.x;
  if (blockIdx.x < NB) {
    int b = blockIdx.x;
    int L = t + 1;
    sQ[tid] = qsa[(size_t)b * DD + tid];
    sQ[tid + 256] = qsa[(size_t)b * DD + tid + 256];
    __syncthreads();
    for (int p = tid; p < NH * L; p += 256) {
      int h = p / L, j = p - h * L;
      const float* kp = Ksa + ((size_t)b * TT + j) * DD + h * DH;
      const float* qp = &sQ[h * DH];
      float a = 0.f;
      #pragma unroll
      for (int i = 0; i < DH; i += 4) {
        float4 kv = *(const float4*)(kp + i);
        a += qp[i] * kv.x + qp[i + 1] * kv.y + qp[i + 2] * kv.z + qp[i + 3] * kv.w;
      }
      sP[h * 64 + j] = a * 0.125f;
    }
    __syncthreads();
    if (tid < NH) {
      float mx = -1e30f;
      for (int j = 0; j < L; j++) mx = fmaxf(mx, sP[tid * 64 + j]);
      float s = 0.f;
      for (int j = 0; j < L; j++) {
        float e = __expf(sP[tid * 64 + j] - mx);
        sP[tid * 64 + j] = e;
        s += e;
      }
      sInv[tid] = 1.f / s;
    }
    __syncthreads();
    for (int d = tid; d < DD; d += 256) {
      int h = d >> 6;
      const float* vp = Vsa + (size_t)b * TT * DD + d;
      float a = 0.f;
      for (int j = 0; j < L; j++) a += sP[h * 64 + j] * vp[(size_t)j * DD];
      attnSA[(size_t)b * DD + d] = a * sInv[h];
    }
  } else {
    int z = blockIdx.x - NB;
    int b = z >> 3, h = z & 7;
    attn_n256(qs + (size_t)b * DD, h, KsT + (size_t)b * NN * DD,
              Vs + (size_t)b * NN * DD, attnS + (size_t)b * DD,
              sQ, sP, sB, redM, redS, tid);
  }
}

// ---- K3: dual Wo GEMV. z=0: u1 = attnSA@saWoT + sa_bo + xcur
//                        z=1: ctx = attnS@sWoT + s_bo ------------------------
__global__ __launch_bounds__(256) void dual_wo(
    const float* __restrict__ saWoT, const float* __restrict__ sWoT,
    const float* __restrict__ attnSA, const float* __restrict__ attnS,
    const float* __restrict__ sa_bo, const float* __restrict__ s_bo,
    const float* __restrict__ xcur,
    float* __restrict__ u1, float* __restrict__ ctx) {
  __shared__ __align__(16) float xs[8][DD];
  int tid = threadIdx.x, jb = blockIdx.x, bg = blockIdx.y, mz = blockIdx.z;
  const float* x = (mz ? attnS : attnSA) + (size_t)bg * 8 * DD;
  const float* W = mz ? sWoT : saWoT;
  #pragma unroll
  for (int q = 0; q < 4; q++) {
    int f = q * 1024 + tid * 4;
    *(float4*)(((float*)xs) + f) = *(const float4*)(x + f);
  }
  __syncthreads();
  int col = jb * 256 + tid;
  const float* wp = W + col;
  float acc[8] = {};
  for (int k = 0; k < DD; k += 4) {
    float w0 = wp[(size_t)(k + 0) * DD];
    float w1 = wp[(size_t)(k + 1) * DD];
    float w2 = wp[(size_t)(k + 2) * DD];
    float w3 = wp[(size_t)(k + 3) * DD];
    #pragma unroll
    for (int bi = 0; bi < 8; bi++) {
      float4 xv = *(const float4*)&xs[bi][k];
      acc[bi] += xv.x * w0 + xv.y * w1 + xv.z * w2 + xv.w * w3;
    }
  }
  if (mz == 0) {
    float bv = sa_bo[col];
    #pragma unroll
    for (int bi = 0; bi < 8; bi++) {
      int b = bg * 8 + bi;
      u1[(size_t)b * DD + col] = acc[bi] + bv + xcur[(size_t)b * DD + col];
    }
  } else {
    float bv = s_bo[col];
    #pragma unroll
    for (int bi = 0; bi < 8; bi++) {
      int b = bg * 8 + bi;
      ctx[(size_t)b * DD + col] = acc[bi] + bv;
    }
  }
}

// ---- K4: LN1 (fused prologue) + caWq GEMV -> qc; jb==0 writes y1 ------------
__global__ __launch_bounds__(256) void ln1_caq(
    const float* __restrict__ u1, const float* __restrict__ lw,
    const float* __restrict__ lb, const float* __restrict__ caWqT,
    const float* __restrict__ ca_bq, float* __restrict__ y1,
    float* __restrict__ qc) {
  __shared__ __align__(16) float xs[8][DD];
  __shared__ float lm[8], li[8];
  int tid = threadIdx.x, jb = blockIdx.x, bg = blockIdx.y;
  const float* xbase = u1 + (size_t)bg * 8 * DD;
  #pragma unroll
  for (int q = 0; q < 4; q++) {
    int f = q * 1024 + tid * 4;
    *(float4*)(((float*)xs) + f) = *(const float4*)(xbase + f);
  }
  __syncthreads();
  ln8_256(xs, lm, li, tid);
  float w0 = lw[tid], w1 = lw[tid + 256], b0 = lb[tid], b1 = lb[tid + 256];
  #pragma unroll
  for (int r = 0; r < 8; r++) {
    float y0 = (xs[r][tid] - lm[r]) * li[r] * w0 + b0;
    float y2 = (xs[r][tid + 256] - lm[r]) * li[r] * w1 + b1;
    xs[r][tid] = y0; xs[r][tid + 256] = y2;
    if (jb == 0) {
      y1[(size_t)(bg * 8 + r) * DD + tid] = y0;
      y1[(size_t)(bg * 8 + r) * DD + tid + 256] = y2;
    }
  }
  __syncthreads();
  int col = jb * 256 + tid;
  const float* wp = caWqT + col;
  float acc[8] = {};
  for (int k = 0; k < DD; k += 4) {
    float v0 = wp[(size_t)(k + 0) * DD];
    float v1 = wp[(size_t)(k + 1) * DD];
    float v2 = wp[(size_t)(k + 2) * DD];
    float v3 = wp[(size_t)(k + 3) * DD];
    #pragma unroll
    for (int bi = 0; bi < 8; bi++) {
      float4 xv = *(const float4*)&xs[bi][k];
      acc[bi] += xv.x * v0 + xv.y * v1 + xv.z * v2 + xv.w * v3;
    }
  }
  float bv = ca_bq[col];
  #pragma unroll
  for (int bi = 0; bi < 8; bi++)
    qc[(size_t)(bg * 8 + bi) * DD + col] = acc[bi] + bv;
}

// ---- K5: cross-attn per (b,h), 256 blocks -----------------------------------
__global__ __launch_bounds__(256) void cross_attn(
    const float* __restrict__ qc, const float* __restrict__ KcT,
    const float* __restrict__ Vc, float* __restrict__ attnCA) {
  __shared__ float sQh[DH];
  __shared__ float sP[256];
  __shared__ float sB[256];
  __shared__ float redM[4], redS[4];
  int tid = threadIdx.x;
  int b = blockIdx.x >> 3, h = blockIdx.x & 7;
  attn_n256(qc + (size_t)b * DD, h, KcT + (size_t)b * NN * DD,
            Vc + (size_t)b * NN * DD, attnCA + (size_t)b * DD,
            sQh, sP, sB, redM, redS, tid);
}

// ---- K6: u2 = attnCA@caWoT + ca_bo + y1 -------------------------------------
__global__ __launch_bounds__(256) void gemv_cawo(
    const float* __restrict__ caWoT, const float* __restrict__ attnCA,
    const float* __restrict__ ca_bo, const float* __restrict__ y1,
    float* __restrict__ u2) {
  __shared__ __align__(16) float xs[8][DD];
  int tid = threadIdx.x, jb = blockIdx.x, bg = blockIdx.y;
  const float* x = attnCA + (size_t)bg * 8 * DD;
  #pragma unroll
  for (int q = 0; q < 4; q++) {
    int f = q * 1024 + tid * 4;
    *(float4*)(((float*)xs) + f) = *(const float4*)(x + f);
  }
  __syncthreads();
  int col = jb * 256 + tid;
  const float* wp = caWoT + col;
  float acc[8] = {};
  for (int k = 0; k < DD; k += 4) {
    float w0 = wp[(size_t)(k + 0) * DD];
    float w1 = wp[(size_t)(k + 1) * DD];
    float w2 = wp[(size_t)(k + 2) * DD];
    float w3 = wp[(size_t)(k + 3) * DD];
    #pragma unroll
    for (int bi = 0; bi < 8; bi++) {
      float4 xv = *(const float4*)&xs[bi][k];
      acc[bi] += xv.x * w0 + xv.y * w1 + xv.z * w2 + xv.w * w3;
    }
  }
  float bv = ca_bo[col];
  #pragma unroll
  for (int bi = 0; bi < 8; bi++) {
    int b = bg * 8 + bi;
    u2[(size_t)b * DD + col] = acc[bi] + bv + y1[(size_t)b * DD + col];
  }
}

// ---- K7: LN2 (fused prologue) + FFN1 (relu); jb==0 writes u3init = z + b2 ---
__global__ __launch_bounds__(256) void ln2_ffn1(
    const float* __restrict__ u2, const float* __restrict__ lw,
    const float* __restrict__ lb, const float* __restrict__ W1t,
    const float* __restrict__ b1, const float* __restrict__ fb2,
    float* __restrict__ hbuf, float* __restrict__ u3) {
  __shared__ __align__(16) float xs[8][DD];
  __shared__ float lm[8], li[8];
  int tid = threadIdx.x, jb = blockIdx.x, bg = blockIdx.y;
  const float* xbase = u2 + (size_t)bg * 8 * DD;
  #pragma unroll
  for (int q = 0; q < 4; q++) {
    int f = q * 1024 + tid * 4;
    *(float4*)(((float*)xs) + f) = *(const float4*)(xbase + f);
  }
  __syncthreads();
  ln8_256(xs, lm, li, tid);
  float w0 = lw[tid], w1 = lw[tid + 256], b0 = lb[tid], b1_ = lb[tid + 256];
  float fb0 = fb2[tid], fb1 = fb2[tid + 256];
  #pragma unroll
  for (int r = 0; r < 8; r++) {
    float z0 = (xs[r][tid] - lm[r]) * li[r] * w0 + b0;
    float z2 = (xs[r][tid + 256] - lm[r]) * li[r] * w1 + b1_;
    xs[r][tid] = z0; xs[r][tid + 256] = z2;
    if (jb == 0) {
      u3[(size_t)(bg * 8 + r) * DD + tid] = z0 + fb0;
      u3[(size_t)(bg * 8 + r) * DD + tid + 256] = z2 + fb1;
    }
  }
  __syncthreads();
  int col = jb * 256 + tid;  // [0, 2048)
  const float* wp = W1t + col;
  float acc[8] = {};
  for (int k = 0; k < DD; k += 4) {
    float v0 = wp[(size_t)(k + 0) * DF];
    float v1 = wp[(size_t)(k + 1) * DF];
    float v2 = wp[(size_t)(k + 2) * DF];
    float v3 = wp[(size_t)(k + 3) * DF];
    #pragma unroll
    for (int bi = 0; bi < 8; bi++) {
      float4 xv = *(const float4*)&xs[bi][k];
      acc[bi] += xv.x * v0 + xv.y * v1 + xv.z * v2 + xv.w * v3;
    }
  }
  float bb = b1[col];
  #pragma unroll
  for (int bi = 0; bi < 8; bi++)
    hbuf[(size_t)(bg * 8 + bi) * DF + col] = fmaxf(acc[bi] + bb, 0.f);
}

// ---- K8: FFN2, split-k x4, atomics into u3 (pre-initialized by K7) ----------
__global__ __launch_bounds__(256) void ffn2(
    const float* __restrict__ W2t, const float* __restrict__ hbuf,
    float* __restrict__ u3) {
  __shared__ __align__(16) float hs[8][DD];
  int tid = threadIdx.x, jb = blockIdx.x, bg = blockIdx.y, ks = blockIdx.z;
  int k0 = ks * 512;
  const float* hbase = hbuf + (size_t)bg * 8 * DF + k0;
  #pragma unroll
  for (int q = 0; q < 4; q++) {
    int f = q * 1024 + tid * 4;
    int r = f >> 9, c = f & 511;
    *(float4*)&hs[r][c] = *(const float4*)(hbase + (size_t)r * DF + c);
  }
  __syncthreads();
  int col = jb * 256 + tid;  // [0, 512)
  const float* wp = W2t + (size_t)k0 * DD + col;
  float acc[8] = {};
  for (int k = 0; k < 512; k += 4) {
    float w0 = wp[(size_t)(k + 0) * DD];
    float w1 = wp[(size_t)(k + 1) * DD];
    float w2 = wp[(size_t)(k + 2) * DD];
    float w3 = wp[(size_t)(k + 3) * DD];
    #pragma unroll
    for (int bi = 0; bi < 8; bi++) {
      float4 hv = *(const float4*)&hs[bi][k];
      acc[bi] += hv.x * w0 + hv.y * w1 + hv.z * w2 + hv.w * w3;
    }
  }
  #pragma unroll
  for (int bi = 0; bi < 8; bi++)
    atomicAdd(&u3[(size_t)(bg * 8 + bi) * DD + col], acc[bi]);
}

// ---- K9: LN3(u3) + ctx -> nxt; xcur update; output projection ---------------
__global__ __launch_bounds__(512) void final_k(
    const float* __restrict__ ctx, const float* __restrict__ u3,
    const float* __restrict__ ln3w, const float* __restrict__ ln3b,
    const float* __restrict__ pe, const float* __restrict__ Wout,
    const float* __restrict__ bout, float* __restrict__ xcur,
    float* __restrict__ out, int t) {
  int b = blockIdx.x, tid = threadIdx.x;
  __shared__ float red[24];
  __shared__ float sN[DD];
  float u = u3[(size_t)b * DD + tid];
  float mean, inv;
  ln_stats512(u, red, tid, mean, inv);
  float nxt = (u - mean) * inv * ln3w[tid] + ln3b[tid] + ctx[(size_t)b * DD + tid];
  sN[tid] = nxt;
  xcur[(size_t)b * DD + tid] = nxt + (t < TT - 1 ? pe[(size_t)(t + 1) * DD + tid] : 0.f);
  __syncthreads();
  if (tid < 128) {
    int c = tid >> 6, l = tid & 63;
    const float* wo = Wout + (size_t)c * DD;
    float a = 0.f;
    #pragma unroll
    for (int i = 0; i < DD / 64; i++) a += sN[l + i * 64] * wo[l + i * 64];
    #pragma unroll
    for (int m = 32; m >= 1; m >>= 1) a += __shfl_xor(a, m);
    if (l == 0) out[((size_t)b * TT + t) * 2 + c] = a + bout[c];
  }
}

// ---------------------------------------------------------------------------
extern "C" void kernel_launch(void* const* d_in, const int* in_sizes, int n_in,
                              void* d_out, int out_size, void* d_ws, size_t ws_size,
                              hipStream_t stream) {
  const float* H_v_all = (const float*)d_in[0];
  const float* H_v0    = (const float*)d_in[1];
  const float* pe      = (const float*)d_in[2];
  const float* s_Wq = (const float*)d_in[3];
  const float* s_Wk = (const float*)d_in[4];
  const float* s_Wv = (const float*)d_in[5];
  const float* s_Wo = (const float*)d_in[6];
  const float* s_bq = (const float*)d_in[7];
  const float* s_bk = (const float*)d_in[8];
  const float* s_bv = (const float*)d_in[9];
  const float* s_bo = (const float*)d_in[10];
  const float* sa_Wq = (const float*)d_in[11];
  const float* sa_Wk = (const float*)d_in[12];
  const float* sa_Wv = (const float*)d_in[13];
  const float* sa_Wo = (const float*)d_in[14];
  const float* sa_bq = (const float*)d_in[15];
  const float* sa_bk = (const float*)d_in[16];
  const float* sa_bv = (const float*)d_in[17];
  const float* sa_bo = (const float*)d_in[18];
  const float* ca_Wq = (const float*)d_in[19];
  const float* ca_Wk = (const float*)d_in[20];
  const float* ca_Wv = (const float*)d_in[21];
  const float* ca_Wo = (const float*)d_in[22];
  const float* ca_bq = (const float*)d_in[23];
  const float* ca_bk = (const float*)d_in[24];
  const float* ca_bv = (const float*)d_in[25];
  const float* ca_bo = (const float*)d_in[26];
  const float* ln1w = (const float*)d_in[27];
  const float* ln1b = (const float*)d_in[28];
  const float* ln2w = (const float*)d_in[29];
  const float* ln2b = (const float*)d_in[30];
  const float* ln3w = (const float*)d_in[31];
  const float* ln3b = (const float*)d_in[32];
  const float* W1   = (const float*)d_in[33];
  const float* b1   = (const float*)d_in[34];
  const float* W2   = (const float*)d_in[35];
  const float* b2   = (const float*)d_in[36];
  const float* Wout = (const float*)d_in[37];
  const float* bout = (const float*)d_in[38];

  float* ws  = (float*)d_ws;
  float* Ks  = ws + OFF_KS;
  float* Vs  = ws + OFF_VS;
  float* Kc  = ws + OFF_KC;
  float* Vc  = ws + OFF_VC;
  float* KsT = ws + OFF_KST;
  float* KcT = ws + OFF_KCT;
  float* Ksa = ws + OFF_KSA;
  float* Vsa = ws + OFF_VSA;
  float* wt8 = ws + OFF_WT;
  float* W1t = ws + OFF_W1T;
  float* W2t = ws + OFF_W2T;
  float* xcur = ws + OFF_X;
  float* qsa  = ws + OFF_QSA;
  float* qsb  = ws + OFF_QS;
  float* aSA  = ws + OFF_ASA;
  float* aSP  = ws + OFF_ASP;
  float* aCA  = ws + OFF_ACA;
  float* u1   = ws + OFF_U1;
  float* y1   = ws + OFF_Y1;
  float* qc   = ws + OFF_QC;
  float* u2   = ws + OFF_U2;
  float* ctx  = ws + OFF_CTX;
  float* u3   = ws + OFF_U3;
  float* hbuf = ws + OFF_H;
  float* out  = (float*)d_out;

  // --- precompute -----------------------------------------------------------
  TPArgs tp;
  tp.m[0] = {sa_Wq, wt8 + 0ull * DD * DD, DD, DD};
  tp.m[1] = {sa_Wk, wt8 + 1ull * DD * DD, DD, DD};
  tp.m[2] = {sa_Wv, wt8 + 2ull * DD * DD, DD, DD};
  tp.m[3] = {sa_Wo, wt8 + 3ull * DD * DD, DD, DD};
  tp.m[4] = {ca_Wq, wt8 + 4ull * DD * DD, DD, DD};
  tp.m[5] = {ca_Wo, wt8 + 5ull * DD * DD, DD, DD};
  tp.m[6] = {s_Wq,  wt8 + 6ull * DD * DD, DD, DD};
  tp.m[7] = {s_Wo,  wt8 + 7ull * DD * DD, DD, DD};
  tp.m[8] = {W1, W1t, DF, DD};
  tp.m[9] = {W2, W2t, DD, DF};
  hipLaunchKernelGGL(transpose_many, dim3(64, 64, 10), dim3(256), 0, stream, tp);

  hipLaunchKernelGGL(gemm_kv, dim3(16, 64), dim3(256), 0, stream,
                     H_v_all, s_Wk, s_Wv, ca_Wk, ca_Wv,
                     s_bk, s_bv, ca_bk, ca_bv, Ks, Vs, Kc, Vc);

  hipLaunchKernelGGL(transpose_kv, dim3(8, 16, 64), dim3(256), 0, stream,
                     Ks, Kc, KsT, KcT);

  hipLaunchKernelGGL(init_x, dim3(64), dim3(256), 0, stream, H_v0, pe, xcur);

  // --- sequential decode ----------------------------------------------------
  for (int t = 0; t < TT; t++) {
    hipLaunchKernelGGL(proj4, dim3(8, 4), dim3(256), 0, stream,
                       wt8, xcur, sa_bq, sa_bk, sa_bv, s_bq,
                       qsa, Ksa, Vsa, qsb, t);
    hipLaunchKernelGGL(attn_self_spatial, dim3(NB + NB * NH), dim3(256), 0, stream,
                       qsa, Ksa, Vsa, qsb, KsT, Vs, aSA, aSP, t);
    hipLaunchKernelGGL(dual_wo, dim3(2, 4, 2), dim3(256), 0, stream,
                       wt8 + 3ull * DD * DD, wt8 + 7ull * DD * DD,
                       aSA, aSP, sa_bo, s_bo, xcur, u1, ctx);
    hipLaunchKernelGGL(ln1_caq, dim3(2, 4), dim3(256), 0, stream,
                       u1, ln1w, ln1b, wt8 + 4ull * DD * DD, ca_bq, y1, qc);
    hipLaunchKernelGGL(cross_attn, dim3(NB * NH), dim3(256), 0, stream,
                       qc, KcT, Vc, aCA);
    hipLaunchKernelGGL(gemv_cawo, dim3(2, 4), dim3(256), 0, stream,
                       wt8 + 5ull * DD * DD, aCA, ca_bo, y1, u2);
    hipLaunchKernelGGL(ln2_ffn1, dim3(8, 4), dim3(256), 0, stream,
                       u2, ln2w, ln2b, W1t, b1, b2, hbuf, u3);
    hipLaunchKernelGGL(ffn2, dim3(2, 4, 4), dim3(256), 0, stream, W2t, hbuf, u3);
    hipLaunchKernelGGL(final_k, dim3(NB), dim3(512), 0, stream,
                       ctx, u3, ln3w, ln3b, pe, Wout, bout, xcur, out, t);
  }
}